// Round 8
// baseline (216.858 us; speedup 1.0000x reference)
//
#include <hip/hip_runtime.h>
#include <hip/hip_bf16.h>
#include <stdint.h>

using frag = __attribute__((ext_vector_type(8))) short;   // 8 bf16 in 4 VGPRs
using f4   = __attribute__((ext_vector_type(4))) float;   // 4 fp32 acc
using bf16 = __hip_bfloat16;

// B=4, T=1024, E=1024, H=16, Dk=64.  Global I/O fp32; compute bf16 MFMA.
static constexpr float WEPS = 1e-5f;
// p = exp(s*sc - 8) = exp2(s*(sc*log2e) - 8*log2e); sc = 0.125*w*w
static constexpr float SC2K  = 0.125f * 1.44269504f;   // 0.18033688
static constexpr float EBIAS = -8.0f * 1.44269504f;    // -11.5415603

#define AS1(p) ((const __attribute__((address_space(1))) void*)(p))
#define AS3(p) ((__attribute__((address_space(3))) void*)(p))

__device__ __forceinline__ void gl2lds16(const void* g, void* l) {
    __builtin_amdgcn_global_load_lds(AS1(g), AS3(l), 16, 0, 0);
}

__device__ inline uint4 pack8(float4 a, float4 b) {
    union { bf16 h[8]; uint4 u; } x;
    x.h[0] = __float2bfloat16(a.x); x.h[1] = __float2bfloat16(a.y);
    x.h[2] = __float2bfloat16(a.z); x.h[3] = __float2bfloat16(a.w);
    x.h[4] = __float2bfloat16(b.x); x.h[5] = __float2bfloat16(b.y);
    x.h[6] = __float2bfloat16(b.z); x.h[7] = __float2bfloat16(b.w);
    return x.u;
}

__device__ __forceinline__ uint2 pack4(float a, float b, float c, float d) {
    union { bf16 h[4]; uint2 u; } x;
    x.h[0] = __float2bfloat16(a); x.h[1] = __float2bfloat16(b);
    x.h[2] = __float2bfloat16(c); x.h[3] = __float2bfloat16(d);
    return x.u;
}

// key-position permutation within each 64-token group:
// pos(j*16+lr) = lr*4+j.  Applied to vhT columns AND P columns identically.
__device__ __forceinline__ int tperm(int t) {
    return (t & ~63) | (((t & 15) << 2) | ((t >> 4) & 3));
}

// ---------------------------------------------------------------------------
// Multi-segment fp32 -> bf16 convert into one contiguous bf16 region.
// ---------------------------------------------------------------------------
struct CvtArgs {
    const float* src[7];
    long long    bounds[8];
    long long    total;
};

__global__ __launch_bounds__(256) void cvt_kernel(CvtArgs a, bf16* __restrict__ dst)
{
    long long e = ((long long)blockIdx.x * 256 + threadIdx.x) * 8;
    if (e >= a.total) return;
    int s = 0;
    while (e >= a.bounds[s + 1]) s++;
    const float* src = a.src[s] + (e - a.bounds[s]);
    float4 f0 = ((const float4*)src)[0];
    float4 f1 = ((const float4*)src)[1];
    *(uint4*)(dst + e) = pack8(f0, f1);
}

// ---------------------------------------------------------------------------
// Batched GEMM, 128x128 tile, BK=32, DOUBLE-BUFFERED LDS (1 barrier/iter:
// prefetch k+1 after the barrier, compute k, barrier -- prefetch had the
// whole compute phase to land, so the barrier's vmcnt drain is cheap).
// XCD swizzle: lid%8 == XCD (presumed); big=(lid&7)*4+(lid>>6) gives each
// XCD a 4(big)x8(small) tile rectangle -> ~3MB/problem working set in L2.
// Out[m,n] = sum_k A[m,k]*W[n,k] + bias[n]
// mode 0: (B,H,T,Dk) bf16 | mode 2: (B,H,Dk,T) scatter (key-permuted)
// mode 3: fp32 row-major  | mode 4: swapped operands -> (B,H,Dk,T) key-permuted
// ---------------------------------------------------------------------------
struct GemmBatch {
    const void*  A[3];
    const void*  W[3];
    const float* bias[3];
    void*        Out[3];
    int          mode[3];
};

template<bool ABF, bool WBF>
__global__ __launch_bounds__(256) void gemm_batch(GemmBatch g)
{
    constexpr int K = 1024;
    __shared__ bf16 As[2][128 * 32];
    __shared__ bf16 Bs[2][128 * 32];

    const int z = blockIdx.z;
    const void*  Ap   = g.A[z];
    const void*  Wp   = g.W[z];
    const float* bias = g.bias[z];
    void*        OutP = g.Out[z];
    const int    mode = g.mode[z];

    const int tid = threadIdx.x;
    const int lid = blockIdx.x + 8 * blockIdx.y;       // 0..255
    const int big   = (lid & 7) * 4 + (lid >> 6);      // 0..31 (XCD-grouped)
    const int small = (lid >> 3) & 7;                  // 0..7
    int m0, n0;
    if (mode == 4) { m0 = small * 128; n0 = big * 128; }
    else           { m0 = big * 128;   n0 = small * 128; }

    const int lane = tid & 63;
    const int wave = tid >> 6;
    const int wm   = (wave >> 1) * 64;
    const int wn   = (wave & 1) * 64;
    const int lr   = lane & 15;
    const int q    = lane >> 4;

    const int sr = tid >> 1;
    const int sc = (tid & 1) * 16;

    const int c0 = wave * 128 + lane;
    const int c1 = c0 + 64;
    const int r0 = c0 >> 2, col0 = (c0 & 3) * 8;
    const int r1 = c1 >> 2, col1 = (c1 & 3) * 8;

    auto stage = [&](int k0, int pb) {
        if (WBF) {
            const bf16* W = (const bf16*)Wp;
            gl2lds16(&W[(size_t)(n0 + r0) * K + k0 + col0], &Bs[pb][wave * 1024]);
            gl2lds16(&W[(size_t)(n0 + r1) * K + k0 + col1], &Bs[pb][wave * 1024 + 512]);
        } else {
            const float* W = (const float*)Wp;
            const float* src = &W[(size_t)(n0 + sr) * K + k0 + sc];
            float4 f0 = ((const float4*)src)[0];
            float4 f1 = ((const float4*)src)[1];
            float4 f2 = ((const float4*)src)[2];
            float4 f3 = ((const float4*)src)[3];
            *(uint4*)(&Bs[pb][sr * 32 + sc])     = pack8(f0, f1);
            *(uint4*)(&Bs[pb][sr * 32 + sc + 8]) = pack8(f2, f3);
        }
        if (ABF) {
            const bf16* A = (const bf16*)Ap;
            gl2lds16(&A[(size_t)(m0 + r0) * K + k0 + col0], &As[pb][wave * 1024]);
            gl2lds16(&A[(size_t)(m0 + r1) * K + k0 + col1], &As[pb][wave * 1024 + 512]);
        } else {
            const float* A = (const float*)Ap;
            const float* src = &A[(size_t)(m0 + sr) * K + k0 + sc];
            float4 f0 = ((const float4*)src)[0];
            float4 f1 = ((const float4*)src)[1];
            float4 f2 = ((const float4*)src)[2];
            float4 f3 = ((const float4*)src)[3];
            *(uint4*)(&As[pb][sr * 32 + sc])     = pack8(f0, f1);
            *(uint4*)(&As[pb][sr * 32 + sc + 8]) = pack8(f2, f3);
        }
    };

    f4 acc[4][4];
    #pragma unroll
    for (int i = 0; i < 4; i++)
        #pragma unroll
        for (int j = 0; j < 4; j++) acc[i][j] = f4{0.f, 0.f, 0.f, 0.f};

    stage(0, 0);
    __syncthreads();

    for (int kt = 0; kt < 32; kt++) {
        const int cb = kt & 1;
        if (kt < 31) stage((kt + 1) * 32, cb ^ 1);

        frag af[4], bfr[4];
        #pragma unroll
        for (int i = 0; i < 4; i++)
            af[i] = *(const frag*)(&As[cb][(wm + i * 16 + lr) * 32 + q * 8]);
        #pragma unroll
        for (int j = 0; j < 4; j++)
            bfr[j] = *(const frag*)(&Bs[cb][(wn + j * 16 + lr) * 32 + q * 8]);
        #pragma unroll
        for (int i = 0; i < 4; i++)
            #pragma unroll
            for (int j = 0; j < 4; j++)
                acc[i][j] = __builtin_amdgcn_mfma_f32_16x16x32_bf16(af[i], bfr[j], acc[i][j], 0, 0, 0);
        __syncthreads();
    }

    // epilogue: D row = quad*4+reg, col = lane&15
    if (mode == 4) {
        const int bbt   = (n0 + wn) >> 10;
        const int tbase = (n0 + wn) & 1023;        // 64-aligned
        bf16* O = (bf16*)OutP;
        #pragma unroll
        for (int i = 0; i < 4; i++) {
            int row0 = m0 + wm + i * 16 + q * 4;
            #pragma unroll
            for (int r = 0; r < 4; r++) {
                int f = row0 + r;                  // feature index
                int h = f >> 6, d = f & 63;
                float bv = bias[f];
                size_t idx = ((((size_t)bbt * 16 + h) * 64 + d) << 10) + tbase + lr * 4;
                *(uint2*)(&O[idx]) = pack4(acc[i][0][r] + bv, acc[i][1][r] + bv,
                                           acc[i][2][r] + bv, acc[i][3][r] + bv);
            }
        }
    } else {
        #pragma unroll
        for (int i = 0; i < 4; i++) {
            int row0 = m0 + wm + i * 16 + q * 4;
            #pragma unroll
            for (int j = 0; j < 4; j++) {
                int col = n0 + wn + j * 16 + lr;
                float bv = bias[col];
                #pragma unroll
                for (int r = 0; r < 4; r++) {
                    float val = acc[i][j][r] + bv;
                    int mrow = row0 + r;
                    if (mode == 3) {
                        ((float*)OutP)[(size_t)mrow * 1024 + col] = val;
                    } else {
                        int bb = mrow >> 10, t = mrow & 1023;
                        int h  = col >> 6,   d = col & 63;
                        size_t idx;
                        if (mode == 2)
                            idx = ((((size_t)bb * 16 + h) * 64 + d) << 10) + tperm(t);
                        else
                            idx = ((((size_t)bb * 16 + h) << 10) + t) * 64 + d;
                        ((bf16*)OutP)[idx] = __float2bfloat16(val);
                    }
                }
            }
        }
    }
}

// ---------------------------------------------------------------------------
// Output GEMM: 64(M) x 128(N) tiles, BK=32, double-buffered, XCD swizzle.
// 512 blocks (2/CU).
// ---------------------------------------------------------------------------
template<bool WBF>
__global__ __launch_bounds__(256) void gemm_out(const bf16* __restrict__ A,
                                                const void* __restrict__ Wp,
                                                const float* __restrict__ bias,
                                                float* __restrict__ Out)
{
    constexpr int K = 1024;
    __shared__ bf16 As[2][64 * 32];
    __shared__ bf16 Bs[2][128 * 32];

    const int tid = threadIdx.x;
    const int lid = blockIdx.x + 8 * blockIdx.y;       // 0..511
    const int mt  = (lid & 7) * 8 + (lid >> 6);        // 0..63 (XCD-grouped)
    const int nt  = (lid >> 3) & 7;                    // 0..7
    const int n0  = nt * 128;
    const int m0  = mt * 64;
    const int lane = tid & 63;
    const int wave = tid >> 6;
    const int wm   = (wave >> 1) * 32;
    const int wn   = (wave & 1) * 64;
    const int lr   = lane & 15;
    const int q    = lane >> 4;

    const int sr = tid >> 1;
    const int sc = (tid & 1) * 16;

    const int c0 = wave * 128 + lane;          // B chunks
    const int c1 = c0 + 64;
    const int r0 = c0 >> 2, col0 = (c0 & 3) * 8;
    const int r1 = c1 >> 2, col1 = (c1 & 3) * 8;
    const int ca = wave * 64 + lane;           // A chunks (256 total)
    const int ra = ca >> 2, cola = (ca & 3) * 8;

    auto stage = [&](int k0, int pb) {
        if (WBF) {
            const bf16* W = (const bf16*)Wp;
            gl2lds16(&W[(size_t)(n0 + r0) * K + k0 + col0], &Bs[pb][wave * 1024]);
            gl2lds16(&W[(size_t)(n0 + r1) * K + k0 + col1], &Bs[pb][wave * 1024 + 512]);
        } else {
            const float* W = (const float*)Wp;
            const float* src = &W[(size_t)(n0 + sr) * K + k0 + sc];
            float4 f0 = ((const float4*)src)[0];
            float4 f1 = ((const float4*)src)[1];
            float4 f2 = ((const float4*)src)[2];
            float4 f3 = ((const float4*)src)[3];
            *(uint4*)(&Bs[pb][sr * 32 + sc])     = pack8(f0, f1);
            *(uint4*)(&Bs[pb][sr * 32 + sc + 8]) = pack8(f2, f3);
        }
        gl2lds16(&A[(size_t)(m0 + ra) * K + k0 + cola], &As[pb][wave * 512]);
    };

    f4 acc[2][4];
    #pragma unroll
    for (int i = 0; i < 2; i++)
        #pragma unroll
        for (int j = 0; j < 4; j++) acc[i][j] = f4{0.f, 0.f, 0.f, 0.f};

    stage(0, 0);
    __syncthreads();

    for (int kt = 0; kt < 32; kt++) {
        const int cb = kt & 1;
        if (kt < 31) stage((kt + 1) * 32, cb ^ 1);

        frag af[2], bfr[4];
        #pragma unroll
        for (int i = 0; i < 2; i++)
            af[i] = *(const frag*)(&As[cb][(wm + i * 16 + lr) * 32 + q * 8]);
        #pragma unroll
        for (int j = 0; j < 4; j++)
            bfr[j] = *(const frag*)(&Bs[cb][(wn + j * 16 + lr) * 32 + q * 8]);
        #pragma unroll
        for (int i = 0; i < 2; i++)
            #pragma unroll
            for (int j = 0; j < 4; j++)
                acc[i][j] = __builtin_amdgcn_mfma_f32_16x16x32_bf16(af[i], bfr[j], acc[i][j], 0, 0, 0);
        __syncthreads();
    }

    #pragma unroll
    for (int i = 0; i < 2; i++) {
        int row0 = m0 + wm + i * 16 + q * 4;
        #pragma unroll
        for (int j = 0; j < 4; j++) {
            int col = n0 + wn + j * 16 + lr;
            float bv = bias[col];
            #pragma unroll
            for (int r = 0; r < 4; r++)
                Out[(size_t)(row0 + r) * 1024 + col] = acc[i][j][r] + bv;
        }
    }
}

// ---------------------------------------------------------------------------
// Flash attention: 32 q-rows/wave (128/block), grid (64 bh, 8 qtiles).
// Fixed-shift softmax (exact), mask folded into exp bias.  P strip padded
// to 72: b128 A-frag reads spread 8/bank.  P stored key-permuted (pos=lr*4+j)
// as one ds_write_b64 per (rf,r); vhT carries the same perm.  Double-buffered
// K/V via glds, 1 barrier/tile.  LDS = 50 KB -> 3 blocks/CU (LDS-capped).
// ---------------------------------------------------------------------------
__global__ __launch_bounds__(256) void attn_kernel(const bf16* __restrict__ qh,
                                                   const bf16* __restrict__ kh,
                                                   const bf16* __restrict__ vhT,
                                                   const float* __restrict__ wts,
                                                   bf16* __restrict__ att)
{
    constexpr int LDP = 72;
    __shared__ bf16 Ks[2][64 * 64];
    __shared__ bf16 Vs[2][64 * 64];
    __shared__ bf16 Plds[4][32 * LDP];

    const int tid  = threadIdx.x;
    const int lane = tid & 63;
    const int wave = tid >> 6;
    const int lr   = lane & 15;
    const int q    = lane >> 4;
    const int bh   = blockIdx.x;               // 0..63
    const int bb   = bh >> 4;
    const int h    = bh & 15;
    const int q0w  = blockIdx.y * 128 + wave * 32;
    const size_t base = (size_t)bh * 1024 * 64;

    const int cA = wave * 128 + lane;
    const int cB = cA + 64;
    const int rowA = cA >> 3, gA = ((cA & 7) ^ (rowA & 7)) * 8;
    const int rowB = cB >> 3, gB = ((cB & 7) ^ (rowB & 7)) * 8;

    frag aq[2][2];
    #pragma unroll
    for (int rf = 0; rf < 2; rf++)
        #pragma unroll
        for (int ks = 0; ks < 2; ks++)
            aq[rf][ks] = *(const frag*)(&qh[base + (size_t)(q0w + rf * 16 + lr) * 64 + ks * 32 + q * 8]);

    float rs[2][4];
    f4 o[2][4];
    #pragma unroll
    for (int rf = 0; rf < 2; rf++)
        #pragma unroll
        for (int j = 0; j < 4; j++) {
            o[rf][j] = f4{0.f, 0.f, 0.f, 0.f};
            rs[rf][j] = 0.f;
        }

    gl2lds16(&kh [base + (size_t)rowA * 64 + gA],   &Ks[0][wave * 1024]);
    gl2lds16(&kh [base + (size_t)rowB * 64 + gB],   &Ks[0][wave * 1024 + 512]);
    gl2lds16(&vhT[base + (size_t)rowA * 1024 + gA], &Vs[0][wave * 1024]);
    gl2lds16(&vhT[base + (size_t)rowB * 1024 + gB], &Vs[0][wave * 1024 + 512]);
    __syncthreads();

    for (int t = 0; t < 16; t++) {
        const int k0  = t * 64;
        const int buf = t & 1;
        if (t < 15) {
            int kn = k0 + 64;
            gl2lds16(&kh [base + (size_t)(kn + rowA) * 64 + gA],  &Ks[buf ^ 1][wave * 1024]);
            gl2lds16(&kh [base + (size_t)(kn + rowB) * 64 + gB],  &Ks[buf ^ 1][wave * 1024 + 512]);
            gl2lds16(&vhT[base + (size_t)rowA * 1024 + kn + gA], &Vs[buf ^ 1][wave * 1024]);
            gl2lds16(&vhT[base + (size_t)rowB * 1024 + kn + gB], &Vs[buf ^ 1][wave * 1024 + 512]);
        }

        // per-key scale; mask folded into bias (exp2(-1e30)=0)
        float sc2[4], eb[4];
        #pragma unroll
        for (int j = 0; j < 4; j++) {
            float w = wts[bb * 1024 + k0 + j * 16 + lr];
            sc2[j] = SC2K * w * w;
            eb[j]  = (w < WEPS) ? -1e30f : EBIAS;
        }

        // K fragments (shared across both row-groups)
        frag kb[4][2];
        #pragma unroll
        for (int j = 0; j < 4; j++) {
            int rowj = j * 16 + lr;
            kb[j][0] = *(const frag*)(&Ks[buf][rowj * 64 + (((q    ) ^ (rowj & 7)) * 8)]);
            kb[j][1] = *(const frag*)(&Ks[buf][rowj * 64 + (((q + 4) ^ (rowj & 7)) * 8)]);
        }

        // S = Q K^T for both 16-row groups
        #pragma unroll
        for (int rf = 0; rf < 2; rf++) {
            f4 s[4];
            #pragma unroll
            for (int j = 0; j < 4; j++) {
                f4 z = f4{0.f, 0.f, 0.f, 0.f};
                s[j] = __builtin_amdgcn_mfma_f32_16x16x32_bf16(aq[rf][0], kb[j][0], z, 0, 0, 0);
                s[j] = __builtin_amdgcn_mfma_f32_16x16x32_bf16(aq[rf][1], kb[j][1], s[j], 0, 0, 0);
            }
            float p[4][4];
            #pragma unroll
            for (int j = 0; j < 4; j++)
                #pragma unroll
                for (int r = 0; r < 4; r++) {
                    p[j][r] = __builtin_amdgcn_exp2f(fmaf(s[j][r], sc2[j], eb[j]));
                    rs[rf][r] += p[j][r];
                }
            #pragma unroll
            for (int r = 0; r < 4; r++)
                *(uint2*)(&Plds[wave][(rf * 16 + q * 4 + r) * LDP + lr * 4]) =
                    pack4(p[0][r], p[1][r], p[2][r], p[3][r]);
        }

        // V fragments (shared across both row-groups)
        frag vb[4][2];
        #pragma unroll
        for (int j = 0; j < 4; j++) {
            int rowj = j * 16 + lr;
            vb[j][0] = *(const frag*)(&Vs[buf][rowj * 64 + (((q    ) ^ (rowj & 7)) * 8)]);
            vb[j][1] = *(const frag*)(&Vs[buf][rowj * 64 + (((q + 4) ^ (rowj & 7)) * 8)]);
        }

        #pragma unroll
        for (int rf = 0; rf < 2; rf++) {
            frag ap0 = *(const frag*)(&Plds[wave][(rf * 16 + lr) * LDP + q * 8]);
            frag ap1 = *(const frag*)(&Plds[wave][(rf * 16 + lr) * LDP + 32 + q * 8]);
            #pragma unroll
            for (int j = 0; j < 4; j++) {
                o[rf][j] = __builtin_amdgcn_mfma_f32_16x16x32_bf16(ap0, vb[j][0], o[rf][j], 0, 0, 0);
                o[rf][j] = __builtin_amdgcn_mfma_f32_16x16x32_bf16(ap1, vb[j][1], o[rf][j], 0, 0, 0);
            }
        }
        __syncthreads();
    }

    #pragma unroll
    for (int off = 1; off < 16; off <<= 1)
        #pragma unroll
        for (int rf = 0; rf < 2; rf++)
            #pragma unroll
            for (int r = 0; r < 4; r++)
                rs[rf][r] += __shfl_xor(rs[rf][r], off, 64);

    #pragma unroll
    for (int rf = 0; rf < 2; rf++) {
        float inv[4];
        #pragma unroll
        for (int r = 0; r < 4; r++) inv[r] = 1.0f / rs[rf][r];
        const int t0 = q0w + rf * 16 + q * 4;
        #pragma unroll
        for (int j = 0; j < 4; j++) {
            int d = h * 64 + j * 16 + lr;
            #pragma unroll
            for (int r = 0; r < 4; r++)
                att[((size_t)bb * 1024 + t0 + r) * 1024 + d] =
                    __float2bfloat16(o[rf][j][r] * inv[r]);
        }
    }
}

// ---------------------------------------------------------------------------
extern "C" void kernel_launch(void* const* d_in, const int* in_sizes, int n_in,
                              void* d_out, int out_size, void* d_ws, size_t ws_size,
                              hipStream_t stream)
{
    const float* q   = (const float*)d_in[0];
    const float* k   = (const float*)d_in[1];
    const float* v   = (const float*)d_in[2];
    const float* wts = (const float*)d_in[3];
    const float* Wq  = (const float*)d_in[4];
    const float* bq  = (const float*)d_in[5];
    const float* Wk  = (const float*)d_in[6];
    const float* bk  = (const float*)d_in[7];
    const float* Wv  = (const float*)d_in[8];
    const float* bv  = (const float*)d_in[9];
    const float* Wo  = (const float*)d_in[10];
    const float* bo  = (const float*)d_in[11];
    float* out = (float*)d_out;

    const long long Mi = 1024 * 1024;
    bf16* qh  = (bf16*)d_ws;
    bf16* kh  = qh  + 4 * Mi;
    bf16* vhT = kh  + 4 * Mi;
    bf16* att = vhT + 4 * Mi;
    bf16* cvt = att + 4 * Mi;
    const size_t base_bytes = (size_t)32 * Mi;

    dim3 blk(256);

    if (ws_size >= base_bytes + (size_t)32 * Mi) {
        // FULL: pre-convert q,k,v + all weights to bf16
        CvtArgs ca{};
        ca.src[0] = q;  ca.src[1] = k;  ca.src[2] = v;
        ca.src[3] = Wq; ca.src[4] = Wk; ca.src[5] = Wv; ca.src[6] = Wo;
        long long bnd[8] = {0, 4*Mi, 8*Mi, 12*Mi, 13*Mi, 14*Mi, 15*Mi, 16*Mi};
        for (int i = 0; i < 8; i++) ca.bounds[i] = bnd[i];
        ca.total = 16 * Mi;
        cvt_kernel<<<8192, blk, 0, stream>>>(ca, cvt);

        GemmBatch gq{};
        gq.A[0] = cvt;          gq.A[1] = cvt + 4*Mi;   gq.A[2] = cvt + 14*Mi; // z2: A=Wv (swapped)
        gq.W[0] = cvt + 12*Mi;  gq.W[1] = cvt + 13*Mi;  gq.W[2] = cvt + 8*Mi;  // z2: W=v
        gq.bias[0] = bq; gq.bias[1] = bk; gq.bias[2] = bv;
        gq.Out[0] = qh;  gq.Out[1] = kh;  gq.Out[2] = vhT;
        gq.mode[0] = 0;  gq.mode[1] = 0;  gq.mode[2] = 4;
        gemm_batch<true, true><<<dim3(8, 32, 3), blk, 0, stream>>>(gq);

        attn_kernel<<<dim3(64, 8), blk, 0, stream>>>(qh, kh, vhT, wts, att);

        gemm_out<true><<<dim3(8, 64), blk, 0, stream>>>(att, cvt + 15*Mi, bo, out);
    } else if (ws_size >= base_bytes + (size_t)8 * Mi) {
        // HYBRID: pre-convert weights only
        CvtArgs ca{};
        ca.src[0] = Wq; ca.src[1] = Wk; ca.src[2] = Wv; ca.src[3] = Wo;
        long long bnd[8] = {0, 1*Mi, 2*Mi, 3*Mi, 4*Mi, 4*Mi, 4*Mi, 4*Mi};
        for (int i = 0; i < 8; i++) ca.bounds[i] = bnd[i];
        ca.total = 4 * Mi;
        cvt_kernel<<<2048, blk, 0, stream>>>(ca, cvt);

        GemmBatch gq{};
        gq.A[0] = q; gq.A[1] = k; gq.A[2] = v;
        gq.W[0] = cvt; gq.W[1] = cvt + 1*Mi; gq.W[2] = cvt + 2*Mi;
        gq.bias[0] = bq; gq.bias[1] = bk; gq.bias[2] = bv;
        gq.Out[0] = qh;  gq.Out[1] = kh;  gq.Out[2] = vhT;
        gq.mode[0] = 0;  gq.mode[1] = 0;  gq.mode[2] = 2;
        gemm_batch<false, true><<<dim3(8, 32, 3), blk, 0, stream>>>(gq);

        attn_kernel<<<dim3(64, 8), blk, 0, stream>>>(qh, kh, vhT, wts, att);

        gemm_out<true><<<dim3(8, 64), blk, 0, stream>>>(att, cvt + 3*Mi, bo, out);
    } else {
        // FALLBACK: no conversions
        GemmBatch gq{};
        gq.A[0] = q; gq.A[1] = k; gq.A[2] = v;
        gq.W[0] = Wq; gq.W[1] = Wk; gq.W[2] = Wv;
        gq.bias[0] = bq; gq.bias[1] = bk; gq.bias[2] = bv;
        gq.Out[0] = qh;  gq.Out[1] = kh;  gq.Out[2] = vhT;
        gq.mode[0] = 0;  gq.mode[1] = 0;  gq.mode[2] = 2;
        gemm_batch<false, false><<<dim3(8, 32, 3), blk, 0, stream>>>(gq);

        attn_kernel<<<dim3(64, 8), blk, 0, stream>>>(qh, kh, vhT, wts, att);

        gemm_out<false><<<dim3(8, 64), blk, 0, stream>>>(att, Wo, bo, out);
    }
}

// Round 9
// 213.583 us; speedup vs baseline: 1.0153x; 1.0153x over previous
//
#include <hip/hip_runtime.h>
#include <hip/hip_bf16.h>
#include <stdint.h>

using frag = __attribute__((ext_vector_type(8))) short;   // 8 bf16 in 4 VGPRs
using f4   = __attribute__((ext_vector_type(4))) float;   // 4 fp32 acc
using bf16 = __hip_bfloat16;

// B=4, T=1024, E=1024, H=16, Dk=64.  Global I/O fp32; compute bf16 MFMA.
static constexpr float WEPS = 1e-5f;
// p = exp(s*sc - 8) = exp2(s*(sc*log2e) - 8*log2e); sc = 0.125*w*w
static constexpr float SC2K  = 0.125f * 1.44269504f;   // 0.18033688
static constexpr float EBIAS = -8.0f * 1.44269504f;    // -11.5415603

#define AS1(p) ((const __attribute__((address_space(1))) void*)(p))
#define AS3(p) ((__attribute__((address_space(3))) void*)(p))

__device__ __forceinline__ void gl2lds16(const void* g, void* l) {
    __builtin_amdgcn_global_load_lds(AS1(g), AS3(l), 16, 0, 0);
}

__device__ inline uint4 pack8(float4 a, float4 b) {
    union { bf16 h[8]; uint4 u; } x;
    x.h[0] = __float2bfloat16(a.x); x.h[1] = __float2bfloat16(a.y);
    x.h[2] = __float2bfloat16(a.z); x.h[3] = __float2bfloat16(a.w);
    x.h[4] = __float2bfloat16(b.x); x.h[5] = __float2bfloat16(b.y);
    x.h[6] = __float2bfloat16(b.z); x.h[7] = __float2bfloat16(b.w);
    return x.u;
}

__device__ __forceinline__ uint2 pack4(float a, float b, float c, float d) {
    union { bf16 h[4]; uint2 u; } x;
    x.h[0] = __float2bfloat16(a); x.h[1] = __float2bfloat16(b);
    x.h[2] = __float2bfloat16(c); x.h[3] = __float2bfloat16(d);
    return x.u;
}

// key-position permutation within each 64-token group:
// pos(j*16+lr) = lr*4+j.  Applied to vhT columns AND P columns identically.
__device__ __forceinline__ int tperm(int t) {
    return (t & ~63) | (((t & 15) << 2) | ((t >> 4) & 3));
}

// ---------------------------------------------------------------------------
// Multi-segment fp32 -> bf16 convert into one contiguous bf16 region.
// ---------------------------------------------------------------------------
struct CvtArgs {
    const float* src[7];
    long long    bounds[8];
    long long    total;
};

__global__ __launch_bounds__(256) void cvt_kernel(CvtArgs a, bf16* __restrict__ dst)
{
    long long e = ((long long)blockIdx.x * 256 + threadIdx.x) * 8;
    if (e >= a.total) return;
    int s = 0;
    while (e >= a.bounds[s + 1]) s++;
    const float* src = a.src[s] + (e - a.bounds[s]);
    float4 f0 = ((const float4*)src)[0];
    float4 f1 = ((const float4*)src)[1];
    *(uint4*)(dst + e) = pack8(f0, f1);
}

// ---------------------------------------------------------------------------
// Batched GEMM, 128x128 tile, BK=32, DOUBLE-BUFFERED LDS (1 barrier/iter).
// XCD swizzle: big=(lid&7)*4+(lid>>6) -> each XCD owns a 4x8 tile rectangle,
// ~3MB/problem L2 working set (r8: FETCH 101->37MB, dur 63->49.5us).
// Out[m,n] = sum_k A[m,k]*W[n,k] + bias[n]
// mode 0: (B,H,T,Dk) bf16 | mode 2: (B,H,Dk,T) scatter (key-permuted)
// mode 3: fp32 row-major  | mode 4: swapped operands -> (B,H,Dk,T) key-permuted
// ---------------------------------------------------------------------------
struct GemmBatch {
    const void*  A[3];
    const void*  W[3];
    const float* bias[3];
    void*        Out[3];
    int          mode[3];
};

template<bool ABF, bool WBF>
__global__ __launch_bounds__(256) void gemm_batch(GemmBatch g)
{
    constexpr int K = 1024;
    __shared__ bf16 As[2][128 * 32];
    __shared__ bf16 Bs[2][128 * 32];

    const int z = blockIdx.z;
    const void*  Ap   = g.A[z];
    const void*  Wp   = g.W[z];
    const float* bias = g.bias[z];
    void*        OutP = g.Out[z];
    const int    mode = g.mode[z];

    const int tid = threadIdx.x;
    const int lid = blockIdx.x + 8 * blockIdx.y;       // 0..255
    const int big   = (lid & 7) * 4 + (lid >> 6);      // 0..31 (XCD-grouped)
    const int small = (lid >> 3) & 7;                  // 0..7
    int m0, n0;
    if (mode == 4) { m0 = small * 128; n0 = big * 128; }
    else           { m0 = big * 128;   n0 = small * 128; }

    const int lane = tid & 63;
    const int wave = tid >> 6;
    const int wm   = (wave >> 1) * 64;
    const int wn   = (wave & 1) * 64;
    const int lr   = lane & 15;
    const int q    = lane >> 4;

    const int sr = tid >> 1;
    const int sc = (tid & 1) * 16;

    const int c0 = wave * 128 + lane;
    const int c1 = c0 + 64;
    const int r0 = c0 >> 2, col0 = (c0 & 3) * 8;
    const int r1 = c1 >> 2, col1 = (c1 & 3) * 8;

    auto stage = [&](int k0, int pb) {
        if (WBF) {
            const bf16* W = (const bf16*)Wp;
            gl2lds16(&W[(size_t)(n0 + r0) * K + k0 + col0], &Bs[pb][wave * 1024]);
            gl2lds16(&W[(size_t)(n0 + r1) * K + k0 + col1], &Bs[pb][wave * 1024 + 512]);
        } else {
            const float* W = (const float*)Wp;
            const float* src = &W[(size_t)(n0 + sr) * K + k0 + sc];
            float4 f0 = ((const float4*)src)[0];
            float4 f1 = ((const float4*)src)[1];
            float4 f2 = ((const float4*)src)[2];
            float4 f3 = ((const float4*)src)[3];
            *(uint4*)(&Bs[pb][sr * 32 + sc])     = pack8(f0, f1);
            *(uint4*)(&Bs[pb][sr * 32 + sc + 8]) = pack8(f2, f3);
        }
        if (ABF) {
            const bf16* A = (const bf16*)Ap;
            gl2lds16(&A[(size_t)(m0 + r0) * K + k0 + col0], &As[pb][wave * 1024]);
            gl2lds16(&A[(size_t)(m0 + r1) * K + k0 + col1], &As[pb][wave * 1024 + 512]);
        } else {
            const float* A = (const float*)Ap;
            const float* src = &A[(size_t)(m0 + sr) * K + k0 + sc];
            float4 f0 = ((const float4*)src)[0];
            float4 f1 = ((const float4*)src)[1];
            float4 f2 = ((const float4*)src)[2];
            float4 f3 = ((const float4*)src)[3];
            *(uint4*)(&As[pb][sr * 32 + sc])     = pack8(f0, f1);
            *(uint4*)(&As[pb][sr * 32 + sc + 8]) = pack8(f2, f3);
        }
    };

    f4 acc[4][4];
    #pragma unroll
    for (int i = 0; i < 4; i++)
        #pragma unroll
        for (int j = 0; j < 4; j++) acc[i][j] = f4{0.f, 0.f, 0.f, 0.f};

    stage(0, 0);
    __syncthreads();

    for (int kt = 0; kt < 32; kt++) {
        const int cb = kt & 1;
        if (kt < 31) stage((kt + 1) * 32, cb ^ 1);

        frag af[4], bfr[4];
        #pragma unroll
        for (int i = 0; i < 4; i++)
            af[i] = *(const frag*)(&As[cb][(wm + i * 16 + lr) * 32 + q * 8]);
        #pragma unroll
        for (int j = 0; j < 4; j++)
            bfr[j] = *(const frag*)(&Bs[cb][(wn + j * 16 + lr) * 32 + q * 8]);
        #pragma unroll
        for (int i = 0; i < 4; i++)
            #pragma unroll
            for (int j = 0; j < 4; j++)
                acc[i][j] = __builtin_amdgcn_mfma_f32_16x16x32_bf16(af[i], bfr[j], acc[i][j], 0, 0, 0);
        __syncthreads();
    }

    // epilogue: D row = quad*4+reg, col = lane&15
    if (mode == 4) {
        const int bbt   = (n0 + wn) >> 10;
        const int tbase = (n0 + wn) & 1023;        // 64-aligned
        bf16* O = (bf16*)OutP;
        #pragma unroll
        for (int i = 0; i < 4; i++) {
            int row0 = m0 + wm + i * 16 + q * 4;
            #pragma unroll
            for (int r = 0; r < 4; r++) {
                int f = row0 + r;                  // feature index
                int h = f >> 6, d = f & 63;
                float bv = bias[f];
                size_t idx = ((((size_t)bbt * 16 + h) * 64 + d) << 10) + tbase + lr * 4;
                *(uint2*)(&O[idx]) = pack4(acc[i][0][r] + bv, acc[i][1][r] + bv,
                                           acc[i][2][r] + bv, acc[i][3][r] + bv);
            }
        }
    } else {
        #pragma unroll
        for (int i = 0; i < 4; i++) {
            int row0 = m0 + wm + i * 16 + q * 4;
            #pragma unroll
            for (int j = 0; j < 4; j++) {
                int col = n0 + wn + j * 16 + lr;
                float bv = bias[col];
                #pragma unroll
                for (int r = 0; r < 4; r++) {
                    float val = acc[i][j][r] + bv;
                    int mrow = row0 + r;
                    if (mode == 3) {
                        ((float*)OutP)[(size_t)mrow * 1024 + col] = val;
                    } else {
                        int bb = mrow >> 10, t = mrow & 1023;
                        int h  = col >> 6,   d = col & 63;
                        size_t idx;
                        if (mode == 2)
                            idx = ((((size_t)bb * 16 + h) * 64 + d) << 10) + tperm(t);
                        else
                            idx = ((((size_t)bb * 16 + h) << 10) + t) * 64 + d;
                        ((bf16*)OutP)[idx] = __float2bfloat16(val);
                    }
                }
            }
        }
    }
}

// ---------------------------------------------------------------------------
// Output GEMM: 64(M) x 128(N) tiles, BK=64 double-buffered (16 MFMA per
// barrier vs 8 at BK=32 -- the worst-amortized kernel in r8).  No XOR
// swizzle: row stride 128B gives 16 accesses/bank on b128 reads (2x the
// 8 min) -- benign per m136; r5 showed swizzle VALU costs more.
// XCD swizzle on block ids.  LDS 48KB; grid 512 = 2 blocks/CU.
// ---------------------------------------------------------------------------
template<bool WBF>
__global__ __launch_bounds__(256) void gemm_out(const bf16* __restrict__ A,
                                                const void* __restrict__ Wp,
                                                const float* __restrict__ bias,
                                                float* __restrict__ Out)
{
    constexpr int K = 1024;
    __shared__ bf16 As[2][64 * 64];     // 16 KB
    __shared__ bf16 Bs[2][128 * 64];    // 32 KB

    const int tid = threadIdx.x;
    const int lid = blockIdx.x + 8 * blockIdx.y;       // 0..511
    const int mt  = (lid & 7) * 8 + (lid >> 6);        // 0..63 (XCD-grouped)
    const int nt  = (lid >> 3) & 7;                    // 0..7
    const int n0  = nt * 128;
    const int m0  = mt * 64;
    const int lane = tid & 63;
    const int wave = tid >> 6;
    const int wm   = (wave >> 1) * 32;
    const int wn   = (wave & 1) * 64;
    const int lr   = lane & 15;
    const int q    = lane >> 4;

    const int sr = tid >> 1;
    const int sc = (tid & 1) * 32;

    // B tile 128x64 = 1024 chunks of 16B (8 chunks/row), 4 per thread
    int rb[4], cb4[4];
    #pragma unroll
    for (int gg = 0; gg < 4; gg++) {
        int D = wave * 256 + gg * 64 + lane;
        rb[gg]  = D >> 3;
        cb4[gg] = (D & 7) * 8;
    }
    // A tile 64x64 = 512 chunks, 2 per thread
    int ra[2], ca4[2];
    #pragma unroll
    for (int gg = 0; gg < 2; gg++) {
        int D = wave * 128 + gg * 64 + lane;
        ra[gg]  = D >> 3;
        ca4[gg] = (D & 7) * 8;
    }

    auto stage = [&](int k0, int pb) {
        if (WBF) {
            const bf16* W = (const bf16*)Wp;
            #pragma unroll
            for (int gg = 0; gg < 4; gg++)
                gl2lds16(&W[(size_t)(n0 + rb[gg]) * K + k0 + cb4[gg]],
                         &Bs[pb][(wave * 256 + gg * 64) * 8]);
        } else {
            const float* W = (const float*)Wp;
            const float* src = &W[(size_t)(n0 + sr) * K + k0 + sc];
            #pragma unroll
            for (int c = 0; c < 4; c++) {
                float4 f0 = ((const float4*)src)[2 * c];
                float4 f1 = ((const float4*)src)[2 * c + 1];
                *(uint4*)(&Bs[pb][sr * 64 + sc + c * 8]) = pack8(f0, f1);
            }
        }
        #pragma unroll
        for (int gg = 0; gg < 2; gg++)
            gl2lds16(&A[(size_t)(m0 + ra[gg]) * K + k0 + ca4[gg]],
                     &As[pb][(wave * 128 + gg * 64) * 8]);
    };

    f4 acc[2][4];
    #pragma unroll
    for (int i = 0; i < 2; i++)
        #pragma unroll
        for (int j = 0; j < 4; j++) acc[i][j] = f4{0.f, 0.f, 0.f, 0.f};

    stage(0, 0);
    __syncthreads();

    for (int kt = 0; kt < 16; kt++) {
        const int cb = kt & 1;
        if (kt < 15) stage((kt + 1) * 64, cb ^ 1);

        #pragma unroll
        for (int kk = 0; kk < 2; kk++) {
            frag af[2], bfr[4];
            #pragma unroll
            for (int i = 0; i < 2; i++)
                af[i] = *(const frag*)(&As[cb][(wm + i * 16 + lr) * 64 + kk * 32 + q * 8]);
            #pragma unroll
            for (int j = 0; j < 4; j++)
                bfr[j] = *(const frag*)(&Bs[cb][(wn + j * 16 + lr) * 64 + kk * 32 + q * 8]);
            #pragma unroll
            for (int i = 0; i < 2; i++)
                #pragma unroll
                for (int j = 0; j < 4; j++)
                    acc[i][j] = __builtin_amdgcn_mfma_f32_16x16x32_bf16(af[i], bfr[j], acc[i][j], 0, 0, 0);
        }
        __syncthreads();
    }

    #pragma unroll
    for (int i = 0; i < 2; i++) {
        int row0 = m0 + wm + i * 16 + q * 4;
        #pragma unroll
        for (int j = 0; j < 4; j++) {
            int col = n0 + wn + j * 16 + lr;
            float bv = bias[col];
            #pragma unroll
            for (int r = 0; r < 4; r++)
                Out[(size_t)(row0 + r) * 1024 + col] = acc[i][j][r] + bv;
        }
    }
}

// ---------------------------------------------------------------------------
// Flash attention: 32 q-rows/wave (128/block), grid (64 bh, 8 qtiles).
// __launch_bounds__(256,3): r8 dropped it and attn fell to 2 blocks/CU
// (natural VGPR > 168) costing ~17us -- pin 3 waves/SIMD (r6/r7 config).
// Fixed-shift softmax (exact), mask folded into exp bias.  P strip padded
// to 72.  P stored key-permuted (pos=lr*4+j) as ds_write_b64; vhT carries
// the same perm.  Double-buffered K/V via glds, 1 barrier/tile.  LDS 50KB.
// ---------------------------------------------------------------------------
__global__ __launch_bounds__(256, 3) void attn_kernel(const bf16* __restrict__ qh,
                                                      const bf16* __restrict__ kh,
                                                      const bf16* __restrict__ vhT,
                                                      const float* __restrict__ wts,
                                                      bf16* __restrict__ att)
{
    constexpr int LDP = 72;
    __shared__ bf16 Ks[2][64 * 64];
    __shared__ bf16 Vs[2][64 * 64];
    __shared__ bf16 Plds[4][32 * LDP];

    const int tid  = threadIdx.x;
    const int lane = tid & 63;
    const int wave = tid >> 6;
    const int lr   = lane & 15;
    const int q    = lane >> 4;
    const int bh   = blockIdx.x;               // 0..63
    const int bb   = bh >> 4;
    const int h    = bh & 15;
    const int q0w  = blockIdx.y * 128 + wave * 32;
    const size_t base = (size_t)bh * 1024 * 64;

    const int cA = wave * 128 + lane;
    const int cB = cA + 64;
    const int rowA = cA >> 3, gA = ((cA & 7) ^ (rowA & 7)) * 8;
    const int rowB = cB >> 3, gB = ((cB & 7) ^ (rowB & 7)) * 8;

    frag aq[2][2];
    #pragma unroll
    for (int rf = 0; rf < 2; rf++)
        #pragma unroll
        for (int ks = 0; ks < 2; ks++)
            aq[rf][ks] = *(const frag*)(&qh[base + (size_t)(q0w + rf * 16 + lr) * 64 + ks * 32 + q * 8]);

    float rs[2][4];
    f4 o[2][4];
    #pragma unroll
    for (int rf = 0; rf < 2; rf++)
        #pragma unroll
        for (int j = 0; j < 4; j++) {
            o[rf][j] = f4{0.f, 0.f, 0.f, 0.f};
            rs[rf][j] = 0.f;
        }

    gl2lds16(&kh [base + (size_t)rowA * 64 + gA],   &Ks[0][wave * 1024]);
    gl2lds16(&kh [base + (size_t)rowB * 64 + gB],   &Ks[0][wave * 1024 + 512]);
    gl2lds16(&vhT[base + (size_t)rowA * 1024 + gA], &Vs[0][wave * 1024]);
    gl2lds16(&vhT[base + (size_t)rowB * 1024 + gB], &Vs[0][wave * 1024 + 512]);
    __syncthreads();

    for (int t = 0; t < 16; t++) {
        const int k0  = t * 64;
        const int buf = t & 1;
        if (t < 15) {
            int kn = k0 + 64;
            gl2lds16(&kh [base + (size_t)(kn + rowA) * 64 + gA],  &Ks[buf ^ 1][wave * 1024]);
            gl2lds16(&kh [base + (size_t)(kn + rowB) * 64 + gB],  &Ks[buf ^ 1][wave * 1024 + 512]);
            gl2lds16(&vhT[base + (size_t)rowA * 1024 + kn + gA], &Vs[buf ^ 1][wave * 1024]);
            gl2lds16(&vhT[base + (size_t)rowB * 1024 + kn + gB], &Vs[buf ^ 1][wave * 1024 + 512]);
        }

        // per-key scale; mask folded into bias (exp2(-1e30)=0)
        float sc2[4], eb[4];
        #pragma unroll
        for (int j = 0; j < 4; j++) {
            float w = wts[bb * 1024 + k0 + j * 16 + lr];
            sc2[j] = SC2K * w * w;
            eb[j]  = (w < WEPS) ? -1e30f : EBIAS;
        }

        // K fragments (shared across both row-groups)
        frag kb[4][2];
        #pragma unroll
        for (int j = 0; j < 4; j++) {
            int rowj = j * 16 + lr;
            kb[j][0] = *(const frag*)(&Ks[buf][rowj * 64 + (((q    ) ^ (rowj & 7)) * 8)]);
            kb[j][1] = *(const frag*)(&Ks[buf][rowj * 64 + (((q + 4) ^ (rowj & 7)) * 8)]);
        }

        // S = Q K^T for both 16-row groups
        #pragma unroll
        for (int rf = 0; rf < 2; rf++) {
            f4 s[4];
            #pragma unroll
            for (int j = 0; j < 4; j++) {
                f4 z = f4{0.f, 0.f, 0.f, 0.f};
                s[j] = __builtin_amdgcn_mfma_f32_16x16x32_bf16(aq[rf][0], kb[j][0], z, 0, 0, 0);
                s[j] = __builtin_amdgcn_mfma_f32_16x16x32_bf16(aq[rf][1], kb[j][1], s[j], 0, 0, 0);
            }
            float p[4][4];
            #pragma unroll
            for (int j = 0; j < 4; j++)
                #pragma unroll
                for (int r = 0; r < 4; r++) {
                    p[j][r] = __builtin_amdgcn_exp2f(fmaf(s[j][r], sc2[j], eb[j]));
                    rs[rf][r] += p[j][r];
                }
            #pragma unroll
            for (int r = 0; r < 4; r++)
                *(uint2*)(&Plds[wave][(rf * 16 + q * 4 + r) * LDP + lr * 4]) =
                    pack4(p[0][r], p[1][r], p[2][r], p[3][r]);
        }

        // V fragments (shared across both row-groups)
        frag vb[4][2];
        #pragma unroll
        for (int j = 0; j < 4; j++) {
            int rowj = j * 16 + lr;
            vb[j][0] = *(const frag*)(&Vs[buf][rowj * 64 + (((q    ) ^ (rowj & 7)) * 8)]);
            vb[j][1] = *(const frag*)(&Vs[buf][rowj * 64 + (((q + 4) ^ (rowj & 7)) * 8)]);
        }

        #pragma unroll
        for (int rf = 0; rf < 2; rf++) {
            frag ap0 = *(const frag*)(&Plds[wave][(rf * 16 + lr) * LDP + q * 8]);
            frag ap1 = *(const frag*)(&Plds[wave][(rf * 16 + lr) * LDP + 32 + q * 8]);
            #pragma unroll
            for (int j = 0; j < 4; j++) {
                o[rf][j] = __builtin_amdgcn_mfma_f32_16x16x32_bf16(ap0, vb[j][0], o[rf][j], 0, 0, 0);
                o[rf][j] = __builtin_amdgcn_mfma_f32_16x16x32_bf16(ap1, vb[j][1], o[rf][j], 0, 0, 0);
            }
        }
        __syncthreads();
    }

    #pragma unroll
    for (int off = 1; off < 16; off <<= 1)
        #pragma unroll
        for (int rf = 0; rf < 2; rf++)
            #pragma unroll
            for (int r = 0; r < 4; r++)
                rs[rf][r] += __shfl_xor(rs[rf][r], off, 64);

    #pragma unroll
    for (int rf = 0; rf < 2; rf++) {
        float inv[4];
        #pragma unroll
        for (int r = 0; r < 4; r++) inv[r] = 1.0f / rs[rf][r];
        const int t0 = q0w + rf * 16 + q * 4;
        #pragma unroll
        for (int j = 0; j < 4; j++) {
            int d = h * 64 + j * 16 + lr;
            #pragma unroll
            for (int r = 0; r < 4; r++)
                att[((size_t)bb * 1024 + t0 + r) * 1024 + d] =
                    __float2bfloat16(o[rf][j][r] * inv[r]);
        }
    }
}

// ---------------------------------------------------------------------------
extern "C" void kernel_launch(void* const* d_in, const int* in_sizes, int n_in,
                              void* d_out, int out_size, void* d_ws, size_t ws_size,
                              hipStream_t stream)
{
    const float* q   = (const float*)d_in[0];
    const float* k   = (const float*)d_in[1];
    const float* v   = (const float*)d_in[2];
    const float* wts = (const float*)d_in[3];
    const float* Wq  = (const float*)d_in[4];
    const float* bq  = (const float*)d_in[5];
    const float* Wk  = (const float*)d_in[6];
    const float* bk  = (const float*)d_in[7];
    const float* Wv  = (const float*)d_in[8];
    const float* bv  = (const float*)d_in[9];
    const float* Wo  = (const float*)d_in[10];
    const float* bo  = (const float*)d_in[11];
    float* out = (float*)d_out;

    const long long Mi = 1024 * 1024;
    bf16* qh  = (bf16*)d_ws;
    bf16* kh  = qh  + 4 * Mi;
    bf16* vhT = kh  + 4 * Mi;
    bf16* att = vhT + 4 * Mi;
    bf16* cvt = att + 4 * Mi;
    const size_t base_bytes = (size_t)32 * Mi;

    dim3 blk(256);

    if (ws_size >= base_bytes + (size_t)32 * Mi) {
        // FULL: pre-convert q,k,v + all weights to bf16
        CvtArgs ca{};
        ca.src[0] = q;  ca.src[1] = k;  ca.src[2] = v;
        ca.src[3] = Wq; ca.src[4] = Wk; ca.src[5] = Wv; ca.src[6] = Wo;
        long long bnd[8] = {0, 4*Mi, 8*Mi, 12*Mi, 13*Mi, 14*Mi, 15*Mi, 16*Mi};
        for (int i = 0; i < 8; i++) ca.bounds[i] = bnd[i];
        ca.total = 16 * Mi;
        cvt_kernel<<<8192, blk, 0, stream>>>(ca, cvt);

        GemmBatch gq{};
        gq.A[0] = cvt;          gq.A[1] = cvt + 4*Mi;   gq.A[2] = cvt + 14*Mi; // z2: A=Wv (swapped)
        gq.W[0] = cvt + 12*Mi;  gq.W[1] = cvt + 13*Mi;  gq.W[2] = cvt + 8*Mi;  // z2: W=v
        gq.bias[0] = bq; gq.bias[1] = bk; gq.bias[2] = bv;
        gq.Out[0] = qh;  gq.Out[1] = kh;  gq.Out[2] = vhT;
        gq.mode[0] = 0;  gq.mode[1] = 0;  gq.mode[2] = 4;
        gemm_batch<true, true><<<dim3(8, 32, 3), blk, 0, stream>>>(gq);

        attn_kernel<<<dim3(64, 8), blk, 0, stream>>>(qh, kh, vhT, wts, att);

        gemm_out<true><<<dim3(8, 64), blk, 0, stream>>>(att, cvt + 15*Mi, bo, out);
    } else if (ws_size >= base_bytes + (size_t)8 * Mi) {
        // HYBRID: pre-convert weights only
        CvtArgs ca{};
        ca.src[0] = Wq; ca.src[1] = Wk; ca.src[2] = Wv; ca.src[3] = Wo;
        long long bnd[8] = {0, 1*Mi, 2*Mi, 3*Mi, 4*Mi, 4*Mi, 4*Mi, 4*Mi};
        for (int i = 0; i < 8; i++) ca.bounds[i] = bnd[i];
        ca.total = 4 * Mi;
        cvt_kernel<<<2048, blk, 0, stream>>>(ca, cvt);

        GemmBatch gq{};
        gq.A[0] = q; gq.A[1] = k; gq.A[2] = v;
        gq.W[0] = cvt; gq.W[1] = cvt + 1*Mi; gq.W[2] = cvt + 2*Mi;
        gq.bias[0] = bq; gq.bias[1] = bk; gq.bias[2] = bv;
        gq.Out[0] = qh;  gq.Out[1] = kh;  gq.Out[2] = vhT;
        gq.mode[0] = 0;  gq.mode[1] = 0;  gq.mode[2] = 2;
        gemm_batch<false, true><<<dim3(8, 32, 3), blk, 0, stream>>>(gq);

        attn_kernel<<<dim3(64, 8), blk, 0, stream>>>(qh, kh, vhT, wts, att);

        gemm_out<true><<<dim3(8, 64), blk, 0, stream>>>(att, cvt + 3*Mi, bo, out);
    } else {
        // FALLBACK: no conversions
        GemmBatch gq{};
        gq.A[0] = q; gq.A[1] = k; gq.A[2] = v;
        gq.W[0] = Wq; gq.W[1] = Wk; gq.W[2] = Wv;
        gq.bias[0] = bq; gq.bias[1] = bk; gq.bias[2] = bv;
        gq.Out[0] = qh;  gq.Out[1] = kh;  gq.Out[2] = vhT;
        gq.mode[0] = 0;  gq.mode[1] = 0;  gq.mode[2] = 2;
        gemm_batch<false, false><<<dim3(8, 32, 3), blk, 0, stream>>>(gq);

        attn_kernel<<<dim3(64, 8), blk, 0, stream>>>(qh, kh, vhT, wts, att);

        gemm_out<false><<<dim3(8, 64), blk, 0, stream>>>(att, Wo, bo, out);
    }
}